// Round 19
// baseline (103.454 us; speedup 1.0000x reference)
//
#include <hip/hip_runtime.h>
#include <cstdint>

#define NB 8
#define NBOX 8732
#define NCL 21
#define NCM1 20
#define LASTD 102
#define CONF_TH 0.5f
#define IOU_TH 0.45f
#define TOPK 200
#define MAXOUT 400     // reference row pitch (flat tie-break encoding)
#define SELCAP 200     // provably sufficient accept cap (== TOPK, r7 proof)
#define EMITN 256      // topk reads within-class ranks [0,256) only
#define NTASK (NB * NCM1)
#define THREADS 1024
#define NW 16
#define NIT 9          // ceil(8732/1024)
#define NBIN 2048
#define KPAD 8768      // full path: counting-sorted keys always fit
#define NBATCH (KPAD / 64)
#define NTR 512        // tranche: bins with suffix-rank < NTR included
#define NMX 576        // matrix dimension (E[examined]=330-410; +5 sigma)
#define NWORD 9        // NMX / 64
#define CPAD 8736      // conf/extra transposed row pitch (16B aligned)

// Exact equivalence (proven): uni>0 && RN_f32(inter/uni) > 0.45f
//   <=>  (double)inter > MIDD*(double)uni   for our operand domain.
// MIDD = double(0.45f) + 2^-26. 25-bit x 24-bit f64 product is exact.
#define MIDD ((double)IOU_TH + 0x1p-26)

// NOTE (r5, r16): device-scope __threadfence() handoff to fuse topk into the
// nms kernel costs ~60-70 us on MI355X (8 non-coherent per-XCD L2s flush) —
// keep topk as a separate kernel.

// Full-path shared state (fallback; r17 structure).
struct SM {
    float4 selbox[SELCAP];
    float selA[SELCAP];
    uint64_t selkey[SELCAP];
    uint64_t keys[KPAD];          // 70.1 KB
    uint64_t smask[2][64];
    unsigned long long extC[2];
    int hist[NBIN];
    int binstart[NBIN];
    int wavetot[NW];
    int Mshare, MtrShare, nselshare, prevNshare, doneflag;
};  // ~93 KB

// Fast-path shared state: bitmask-NMS over the top-NMX tranche.
struct FastSM {
    uint64_t keys[NMX];           // 4.6 KB
    uint64_t M[NMX][NWORD];       // 40.5 KB: M[a][w] bit b = "a suppresses b"
    float4 bx[NMX];               // 9.2 KB
    float ar[NMX];                // 2.3 KB
    int acc[SELCAP];              // accepted candidate indices, rank order
    int hist[NBIN];               // 8 KB
    int binstart[NBIN];           // 8 KB
    int wavetot[NW];
    int Mshare, MtrShare, nselshare;
};  // ~75 KB

__device__ __forceinline__ int iou_sup(float4 a, float aA, float4 b, float bA) {
    float x1 = fmaxf(a.x, b.x), y1 = fmaxf(a.y, b.y);
    float x2 = fminf(a.z, b.z), y2 = fminf(a.w, b.w);
    float iw = fmaxf(__fsub_rn(x2, x1), 0.0f);
    float ih = fmaxf(__fsub_rn(y2, y1), 0.0f);
    float inter = __fmul_rn(iw, ih);
    float uni = __fsub_rn(__fadd_rn(aA, bA), inter);
    return (double)inter > MIDD * (double)uni;
}

__device__ __forceinline__ float4 load_box(const float* __restrict__ img,
                                           int boxoff, uint64_t key) {
    if ((key >> 32) == 0) return make_float4(0.f, 0.f, 0.f, 0.f);
    uint32_t i = 0xFFFFFFFFu - (uint32_t)key;
    const float* bp = img + (size_t)i * LASTD + boxoff;
    return make_float4(bp[0], bp[1], bp[2], bp[3]);
}

__device__ __forceinline__ float box_area(float4 b) {
    return __fmul_rn(__fsub_rn(b.z, b.x), __fsub_rn(b.w, b.y));
}

__device__ __forceinline__ float4 shfl_box(float4 b, int c) {
    float4 r;
    r.x = __shfl(b.x, c); r.y = __shfl(b.y, c);
    r.z = __shfl(b.z, c); r.w = __shfl(b.w, c);
    return r;
}

__device__ __forceinline__ uint64_t shfl_xor_u64(uint64_t v, int m) {
    return (uint64_t)__shfl_xor((unsigned long long)v, m, 64);
}

// Full-bandwidth layout pass: stream y_pred coalesced, scatter conf columns
// 1..20 into confT and column 101 into extraT.
__global__ __launch_bounds__(256) void transpose_conf(const float* __restrict__ yp,
                                                      float* __restrict__ confT,
                                                      float* __restrict__ extraT) {
    const uint32_t TOT4 = (uint32_t)NB * NBOX * LASTD / 4u;
    for (uint32_t i4 = blockIdx.x * blockDim.x + threadIdx.x; i4 < TOT4;
         i4 += gridDim.x * blockDim.x) {
        float4 v = ((const float4*)yp)[i4];
        uint32_t base = i4 * 4u;
        #pragma unroll
        for (int k = 0; k < 4; ++k) {
            uint32_t flat = base + k;
            uint32_t b = flat / (NBOX * LASTD);
            uint32_t rem = flat - b * (NBOX * LASTD);
            uint32_t row = rem / LASTD;
            uint32_t col = rem - row * LASTD;
            float f = (k == 0) ? v.x : (k == 1) ? v.y : (k == 2) ? v.z : v.w;
            if (col - 1u < (uint32_t)NCM1)
                confT[((size_t)b * NCM1 + (col - 1u)) * CPAD + row] = f;
            else if (col == LASTD - 1)
                extraT[(size_t)b * CPAD + row] = f;
        }
    }
}

// 2048-bin counting sort of conf>0.5 candidates into (score desc, idx asc)
// order, written into sm.keys[0..PADT) zero-padded. TRM: only bins with
// suffix-rank < NTRT are scattered/sorted (exact prefix of the full order).
template <class SMT, bool TRM, int PADT, int NTRT>
__device__ void build_keys_impl(const float* __restrict__ confsrc, int cstride,
                                SMT& sm, int tid, int lane, int wav,
                                int& M, int& Mtr) {
    float confs[NIT];
    #pragma unroll
    for (int it = 0; it < NIT; ++it) {
        int idx = it * THREADS + tid;
        confs[it] = (idx < NBOX) ? confsrc[(size_t)idx * cstride] : 0.0f;
    }
    sm.hist[tid] = 0; sm.hist[tid + THREADS] = 0;
    if (tid == 0) sm.MtrShare = 0;
    __syncthreads();

    #pragma unroll
    for (int it = 0; it < NIT; ++it) {
        int idx = it * THREADS + tid;
        if (idx < NBOX && confs[it] > CONF_TH) {
            int bin = (int)((__float_as_uint(confs[it]) - 0x3F000000u) >> 12);
            atomicAdd(&sm.hist[bin], 1);
        }
    }
    __syncthreads();

    // descending bin bases via suffix-sum over bin pairs
    int h0 = sm.hist[2 * tid], h1 = sm.hist[2 * tid + 1];
    int x = h0 + h1;
    int s = x;
    #pragma unroll
    for (int d = 1; d <= 32; d <<= 1) {
        int y = __shfl_down(s, d);
        if (lane + d < 64) s += y;
    }
    if (lane == 0) sm.wavetot[wav] = s;
    __syncthreads();
    int cross = 0;
    #pragma unroll
    for (int w = 0; w < NW; ++w)
        if (w > wav) cross += sm.wavetot[w];
    int Safter = cross + s - x;               // keys in bins strictly above
    sm.binstart[2 * tid + 1] = Safter;        // higher bin (higher score) first
    sm.binstart[2 * tid] = Safter + h1;
    if (tid == 0) sm.Mshare = cross + s;
    if (TRM) {
        int cand = 0;
        if (Safter < NTRT && h1 > 0) cand = Safter + h1;
        int bs0 = Safter + h1;
        if (bs0 < NTRT && h0 > 0) { int c2 = bs0 + h0; cand = cand > c2 ? cand : c2; }
        if (cand > 0) atomicMax(&sm.MtrShare, cand);
    }
    sm.hist[2 * tid] = 0; sm.hist[2 * tid + 1] = 0;  // reuse as scatter ctr
    __syncthreads();
    M = sm.Mshare;
    Mtr = TRM ? sm.MtrShare : M;

    #pragma unroll
    for (int it = 0; it < NIT; ++it) {
        int idx = it * THREADS + tid;
        if (idx < NBOX && confs[it] > CONF_TH) {
            uint32_t bits = __float_as_uint(confs[it]);
            int bin = (int)((bits - 0x3F000000u) >> 12);
            if (!TRM || sm.binstart[bin] < NTRT) {
                int slot = sm.binstart[bin] + atomicAdd(&sm.hist[bin], 1);
                if (!TRM || slot < PADT)
                    sm.keys[slot] = ((uint64_t)bits << 32) |
                                    (uint32_t)(0xFFFFFFFFu - (uint32_t)idx);
            }
        }
    }
    __syncthreads();
    int Mp = Mtr < PADT ? Mtr : PADT;
    for (int m = Mp + tid; m < PADT; m += THREADS) sm.keys[m] = 0;
    for (int f = tid; f < NBIN; f += THREADS) {
        int s0 = sm.binstart[f], h = sm.hist[f];
        if (TRM && (s0 >= NTRT || s0 + h > PADT)) continue;
        for (int i2 = 1; i2 < h; ++i2) {
            uint64_t key = sm.keys[s0 + i2];
            int j = i2 - 1;
            while (j >= 0 && sm.keys[s0 + j] < key) {
                sm.keys[s0 + j + 1] = sm.keys[s0 + j];
                --j;
            }
            sm.keys[s0 + j + 1] = key;
        }
    }
    __syncthreads();
}

// Fallback scan (r17 structure): two-barrier pipelined greedy, chunk-major
// full-check, ext-gated suppressor masks. Exact argmax+suppress replica.
template <int KPADT, int NBATCHT>
__device__ int greedy_scan(const float* __restrict__ img, int boxoff, SM& sm,
                           int tid, int lane, int wav) {
    uint64_t keyC = sm.keys[lane];
    uint64_t keyN = sm.keys[64 + lane];
    float4 boxC = load_box(img, boxoff, keyC);
    float4 boxN = load_box(img, boxoff, keyN);
    float aC = box_area(boxC), aN = box_area(boxN);
    #pragma unroll
    for (int tt = 0; tt < 4; ++tt) {
        int c = wav + tt * NW;
        float4 cb = shfl_box(boxC, c);
        float ca = __shfl(aC, c);
        uint64_t row = 0;
        if (ca > 0.0f)
            row = __ballot(lane < c && iou_sup(cb, ca, boxC, aC));
        if (lane == 0) sm.smask[0][c] = row;
    }
    if (tid == 0) { sm.extC[0] = 0ull; sm.extC[1] = 0ull; }
    __syncthreads();

    int nsel = 0, prevN = 0;
    bool done = false;
    for (int i = 0; i < NBATCHT && !done; ++i) {
        const int p = i & 1;
        const bool vC = (keyC >> 32) != 0;
        {
            int sup = 0;
            for (int j = prevN + wav; j < nsel; j += NW)
                sup |= iou_sup(boxC, aC, sm.selbox[j], sm.selA[j]);
            unsigned long long bal = __ballot(vC && sup);
            if (lane == 0 && bal) atomicOr(&sm.extC[p], bal);
        }
        int f0 = (i + 2) * 64;
        uint64_t key2 = (f0 < KPADT) ? sm.keys[f0 + lane] : 0;
        float4 box2 = load_box(img, boxoff, key2);
        float a2 = box_area(box2);
        __syncthreads();
        const int nselPre = nsel;
        if (wav == 0) {
            unsigned long long V = __ballot(vC);
            unsigned long long E = sm.extC[p];
            if (lane == 0) sm.extC[p] = 0ull;
            uint64_t smc = sm.smask[p][lane];
            uint64_t alive = ~(E | ~V);
            uint64_t accm = 0;
            int cnt = nsel;
            while (alive && cnt < SELCAP) {
                int t = __ffsll((unsigned long long)alive) - 1;
                uint64_t bit = 1ull << t;
                accm |= bit;
                cnt++;
                unsigned long long kill = __ballot((smc >> t) & 1ull);
                alive &= ~(kill | bit);
            }
            if ((accm >> lane) & 1ull) {
                int pos = nsel + __popcll(accm & ((1ull << lane) - 1ull));
                sm.selbox[pos] = boxC;
                sm.selA[pos] = aC;
                sm.selkey[pos] = keyC;
            }
            if (lane == 0) {
                sm.nselshare = cnt;
                sm.prevNshare = nsel;
                sm.doneflag = (cnt >= SELCAP) || (V != ~0ull);
            }
        } else {
            float4 cb[5];
            float ca[5];
            unsigned amask = 0;
            #pragma unroll
            for (int k = 0; k < 5; ++k) {
                int c = (wav - 1) + k * (NW - 1);
                float4 t4 = make_float4(0.f, 0.f, 0.f, 0.f);
                float tA = 0.0f;
                if (c < 64) {
                    t4 = shfl_box(boxN, c);
                    tA = __shfl(aN, c);
                }
                cb[k] = t4; ca[k] = tA;
                if (c < 64 && tA > 0.0f) amask |= 1u << k;
            }
            unsigned long long sb = 0;
            for (int j0 = 0; j0 < nselPre && amask; j0 += 64) {
                int j = j0 + lane;
                bool jv = j < nselPre;
                float4 sbx = sm.selbox[jv ? j : 0];
                float sA = sm.selA[jv ? j : 0];
                #pragma unroll
                for (int k = 0; k < 5; ++k) {
                    if (!((amask >> k) & 1u)) continue;
                    int hit = jv && iou_sup(cb[k], ca[k], sbx, sA);
                    if (__ballot(hit)) {
                        amask &= ~(1u << k);
                        sb |= 1ull << ((wav - 1) + k * (NW - 1));
                    }
                }
            }
            #pragma unroll
            for (int k = 0; k < 5; ++k) {
                if (!((amask >> k) & 1u)) continue;
                int c = (wav - 1) + k * (NW - 1);
                uint64_t row = __ballot(lane < c && iou_sup(cb[k], ca[k], boxN, aN));
                if (lane == 0) sm.smask[p ^ 1][c] = row;
            }
            if (lane == 0 && sb) atomicOr(&sm.extC[p ^ 1], sb);
        }
        __syncthreads();
        nsel = sm.nselshare;
        prevN = sm.prevNshare;
        done = sm.doneflag != 0;
        keyC = keyN; boxC = boxN; aC = aN;
        keyN = key2; boxN = box2; aN = a2;
    }
    return nsel;
}

// Fallback emit (full path).
__device__ void emit_rows(const float* __restrict__ extrasrc, int estride,
                          int cm1, SM& sm, int nsel, float* __restrict__ rows,
                          int task, int tid) {
    float* out0 = rows + (size_t)task * MAXOUT * 7;
    for (int r = tid; r < EMITN; r += THREADS) {
        float* o = out0 + (size_t)r * 7;
        if (r < nsel) {
            uint64_t key = sm.selkey[r];
            uint32_t i = 0xFFFFFFFFu - (uint32_t)key;
            float4 bx = sm.selbox[r];
            o[0] = (float)(cm1 + 1);
            o[1] = __uint_as_float((uint32_t)(key >> 32));
            o[2] = bx.x;
            o[3] = bx.y;
            o[4] = bx.z;
            o[5] = bx.w;
            o[6] = extrasrc[(size_t)i * estride];
        } else {
            #pragma unroll
            for (int q = 0; q < 7; ++q) o[q] = 0.0f;
        }
    }
}

// Main NMS kernel — bitmask-NMS fast path:
//  1) tranche counting-sort of top-NMX candidates (exact sorted prefix)
//  2) gather boxes to LDS; compute upper-triangle suppression matrix M
//     (M[a][w] bit b: a suppresses b, b>a) with all 16 waves in parallel
//  3) zero-barrier serial greedy sweep on wave0: t=first alive, accept,
//     alive &= ~M[t] — EXACTLY the reference argmax+suppress recurrence
//     (sorted order = argmax order; ties idx-asc in the key). Lower-triangle
//     garbage in M is harmless: those bits are already 0 in alive when read.
//  4) emit from the accept list.
// Guarded fallback to the full-path build+scan when the tranche can't decide.
__global__ __launch_bounds__(THREADS) void nms_fast(const float* __restrict__ yp,
                                                    const float* __restrict__ confT,
                                                    const float* __restrict__ extraT,
                                                    float* __restrict__ rows) {
    __shared__ union USM { SM full; FastSM fast; } u;
    const int task = blockIdx.x;
    const int b = task / NCM1;
    const int cm1 = task % NCM1;
    const int tid = threadIdx.x;
    const int lane = tid & 63;
    const int wav = tid >> 6;
    const float* img = yp + (size_t)b * NBOX * LASTD;
    const float* conf = confT + (size_t)task * CPAD;
    const int boxoff = NCL + 4 * cm1;

    int M, Mtr;
    build_keys_impl<FastSM, true, NMX, NTR>(conf, 1, u.fast, tid, lane, wav,
                                            M, Mtr);
    int nsel = -1;
    if (Mtr <= NMX) {                       // block-uniform
        // gather candidate boxes (zero keys -> zero box, area 0)
        for (int c = tid; c < NMX; c += THREADS) {
            float4 bb = load_box(img, boxoff, u.fast.keys[c]);
            u.fast.bx[c] = bb;
            u.fast.ar[c] = box_area(bb);
        }
        __syncthreads();
        // pairwise suppression matrix: wave handles rows a = wav + 16k
        for (int k = 0; k < NMX / NW; ++k) {
            int a = wav + k * NW;
            float4 ab = u.fast.bx[a];       // broadcast LDS read
            float aa = u.fast.ar[a];
            if (aa > 0.0f) {                // wave-uniform
                for (int w = a >> 6; w < NWORD; ++w) {
                    int bc = w * 64 + lane;
                    int hit = (bc > a) &&
                              iou_sup(ab, aa, u.fast.bx[bc], u.fast.ar[bc]);
                    unsigned long long bal = __ballot(hit);
                    if (lane == 0) u.fast.M[a][w] = bal;
                }
            } else {                        // dead row: zero (never consulted)
                for (int w = a >> 6; w < NWORD; ++w)
                    if (lane == 0) u.fast.M[a][w] = 0ull;
            }
        }
        __syncthreads();
        // serial greedy sweep on wave0 (word-major, ~55 cy/accept)
        if (wav == 0) {
            uint64_t alive = 0;
            if (lane < NWORD) {
                int rem = Mtr - lane * 64;
                alive = (rem >= 64) ? ~0ull
                      : (rem > 0 ? ((1ull << rem) - 1ull) : 0ull);
            }
            int cnt = 0;
            for (int w = 0; w < NWORD && cnt < SELCAP; ++w) {
                uint64_t cur = (uint64_t)__shfl((unsigned long long)alive, w);
                while (cur && cnt < SELCAP) {
                    int t = __ffsll((unsigned long long)cur) - 1;
                    int c = w * 64 + t;
                    if (lane == 0) u.fast.acc[cnt] = c;
                    cnt++;
                    uint64_t row = (lane < NWORD) ? u.fast.M[c][lane] : 0ull;
                    alive &= ~row;          // kills into later words
                    uint64_t roww = (uint64_t)__shfl((unsigned long long)row, w);
                    cur &= ~(roww | (1ull << t));
                }
            }
            if (lane == 0) u.fast.nselshare = cnt;
        }
        __syncthreads();
        nsel = u.fast.nselshare;
        if (nsel < SELCAP && Mtr < M) nsel = -1;   // tranche insufficient
        if (nsel >= 0) {
            const float* extrasrc = extraT + (size_t)b * CPAD;
            float* out0 = rows + (size_t)task * MAXOUT * 7;
            for (int r = tid; r < EMITN; r += THREADS) {
                float* o = out0 + (size_t)r * 7;
                if (r < nsel) {
                    int c = u.fast.acc[r];
                    uint64_t key = u.fast.keys[c];
                    uint32_t i = 0xFFFFFFFFu - (uint32_t)key;
                    float4 bxv = u.fast.bx[c];
                    o[0] = (float)(cm1 + 1);
                    o[1] = __uint_as_float((uint32_t)(key >> 32));
                    o[2] = bxv.x;
                    o[3] = bxv.y;
                    o[4] = bxv.z;
                    o[5] = bxv.w;
                    o[6] = extrasrc[i];
                } else {
                    #pragma unroll
                    for (int q = 0; q < 7; ++q) o[q] = 0.0f;
                }
            }
        }
    }
    if (nsel < 0) {                         // exact full path (P ~ 0)
        __syncthreads();                    // quiesce fast-view reads
        int M2, Mt2;
        build_keys_impl<SM, false, KPAD, 0>(conf, 1, u.full, tid, lane, wav,
                                            M2, Mt2);
        int ns2 = greedy_scan<KPAD, NBATCH>(img, boxoff, u.full, tid, lane, wav);
        emit_rows(extraT + (size_t)b * CPAD, 1, cm1, u.full, ns2, rows, task,
                  tid);
    }
}

// Fallback monolith (direct strided gathers, full sort) if ws too small.
__global__ __launch_bounds__(THREADS) void nms_mono(const float* __restrict__ yp,
                                                    float* __restrict__ rows) {
    __shared__ SM sm;
    const int task = blockIdx.x;
    const int b = task / NCM1;
    const int cm1 = task % NCM1;
    const int tid = threadIdx.x;
    const float* img = yp + (size_t)b * NBOX * LASTD;
    int M, Mtr;
    build_keys_impl<SM, false, KPAD, 0>(img + 1 + cm1, LASTD, sm, tid,
                                        tid & 63, tid >> 6, M, Mtr);
    int nsel = greedy_scan<KPAD, NBATCH>(img, NCL + 4 * cm1, sm, tid,
                                         tid & 63, tid >> 6);
    emit_rows(img + (LASTD - 1), LASTD, cm1, sm, nsel, rows, task, tid);
}

// One block per image: top-200 by (conf desc, flat idx asc). Per-class lists
// are score-desc; top-200 never needs within-class rank >= 256: 32 lists x
// 256 keys, 5 rounds of bitonic top-256 merges; j<=32 stages fused in
// registers via shfl_xor.
__global__ __launch_bounds__(THREADS) void topk_per_image(const float* __restrict__ rows,
                                                          float* __restrict__ out) {
    __shared__ uint64_t K[8192];
    const int b = blockIdx.x;
    const int tid = threadIdx.x;
    const float* rb = rows + (size_t)b * (NCM1 * MAXOUT) * 7;

    for (int xx = tid; xx < 8192; xx += THREADS) {
        int list = xx >> 8, r = xx & 255;
        uint64_t k = 0;
        if (list < NCM1) {
            int flat = list * MAXOUT + r;
            float conf = rb[(size_t)flat * 7 + 1];
            k = ((uint64_t)__float_as_uint(conf) << 32) |
                (uint32_t)(0xFFFFFFFFu - (uint32_t)flat);
        }
        K[xx] = k;
    }
    __syncthreads();

    for (int round = 0; round < 5; ++round) {
        int npairs = 16 >> round;
        int sep = 256 << round;
        for (int w = tid; w < npairs * 256; w += THREADS) {
            int p = w >> 8, t = w & 255;
            int A = p * 2 * sep;
            uint64_t a = K[A + t];
            uint64_t c = K[A + sep + 255 - t];
            K[A + t] = a > c ? a : c;
        }
        __syncthreads();
        for (int j = 128; j >= 64; j >>= 1) {
            for (int w = tid; w < npairs * 128; w += THREADS) {
                int p = w >> 7, q = w & 127;
                int t = ((q & ~(j - 1)) << 1) | (q & (j - 1));
                int A = p * 2 * sep;
                uint64_t x0 = K[A + t];
                uint64_t x1 = K[A + t + j];
                if (x0 < x1) { K[A + t] = x1; K[A + t + j] = x0; }
            }
            __syncthreads();
        }
        for (int w = tid; w < npairs * 256; w += THREADS) {
            int p = w >> 8, t = w & 255;
            int xI = p * 2 * sep + t;
            uint64_t v = K[xI];
            #pragma unroll
            for (int j = 32; j >= 1; j >>= 1) {
                uint64_t pr = shfl_xor_u64(v, j);
                uint64_t mx = v > pr ? v : pr;
                uint64_t mn = v > pr ? pr : v;
                v = ((t & j) == 0) ? mx : mn;
            }
            K[xI] = v;
        }
        __syncthreads();
    }

    if (tid < TOPK) {
        uint64_t key = K[tid];
        uint32_t flat = 0xFFFFFFFFu - (uint32_t)key;
        const float* src = rb + (size_t)flat * 7;
        float* o = out + ((size_t)b * TOPK + tid) * 7;
        #pragma unroll
        for (int q = 0; q < 7; ++q) o[q] = src[q];
    }
}

extern "C" void kernel_launch(void* const* d_in, const int* in_sizes, int n_in,
                              void* d_out, int out_size, void* d_ws, size_t ws_size,
                              hipStream_t stream) {
    const float* yp = (const float*)d_in[0];
    float* rows = (float*)d_ws;
    const size_t rowsB = (size_t)NTASK * MAXOUT * 7 * sizeof(float);   // 1.792 MB
    float* confT = (float*)((char*)d_ws + rowsB);
    const size_t confB = (size_t)NTASK * CPAD * sizeof(float);         // 5.59 MB
    float* extraT = (float*)((char*)confT + confB);
    const size_t extraB = (size_t)NB * CPAD * sizeof(float);           // 0.28 MB
    const size_t need = rowsB + confB + extraB;                        // ~7.7 MB
    float* out = (float*)d_out;

    if (ws_size >= need) {
        hipLaunchKernelGGL(transpose_conf, dim3(2048), dim3(256), 0, stream,
                           yp, confT, extraT);
        hipLaunchKernelGGL(nms_fast, dim3(NTASK), dim3(THREADS), 0, stream,
                           yp, confT, extraT, rows);
    } else {
        hipLaunchKernelGGL(nms_mono, dim3(NTASK), dim3(THREADS), 0, stream,
                           yp, rows);
    }
    hipLaunchKernelGGL(topk_per_image, dim3(NB), dim3(THREADS), 0, stream,
                       rows, out);
}

// Round 20
// 55.904 us; speedup vs baseline: 1.8506x; 1.8506x over previous
//
#include <hip/hip_runtime.h>
#include <cstdint>

#define NB 8
#define NBOX 8732
#define NCL 21
#define NCM1 20
#define LASTD 102
#define CONF_TH 0.5f
#define IOU_TH 0.45f
#define TOPK 200
#define MAXOUT 400     // reference row pitch (flat tie-break encoding)
#define SELCAP 200     // provably sufficient accept cap (== TOPK, r7 proof)
#define EMITN 256      // topk reads within-class ranks [0,256) only
#define NTASK (NB * NCM1)
#define THREADS 1024
#define NW 16
#define NIT 9          // ceil(8732/1024)
#define NBIN 2048
#define KPAD 8768      // full path: counting-sorted keys always fit
#define NBATCH (KPAD / 64)
#define NTR 512        // tranche: bins with suffix-rank < NTR (E[exam]≈330)
#define KPAD_TR (NTR + 128)
#define NBATCH_TR (KPAD_TR / 64)
#define CPAD 8736      // conf/extra transposed row pitch (16B aligned)
#define TROWS 64       // transpose tile rows
#define NTILE ((NBOX + TROWS - 1) / TROWS)   // 137
#define TSLOT 21       // 20 conf cols + extra
#define TPITCH 68      // 64 + 4 pad (bank-conflict-free)

// Exact equivalence (proven): uni>0 && RN_f32(inter/uni) > 0.45f
//   <=>  (double)inter > MIDD*(double)uni   for our operand domain.
// MIDD = double(0.45f) + 2^-26. 25-bit x 24-bit f64 product is exact.
#define MIDD ((double)IOU_TH + 0x1p-26)

// NOTE (r5, r16): device-scope __threadfence() handoff to fuse topk into the
// nms kernel costs ~60-70 us on MI355X (8 non-coherent per-XCD L2s flush) —
// keep topk as a separate kernel.
// NOTE (r19): bitmask-NMS (full pairwise matrix + serial sweep) is 2x SLOWER
// than the pipelined scan: matrix pair-work >> early-exit pair-work, and the
// sweep's per-accept ds_read chain (~200cy) beats resolve's ballot (~70cy).

struct SM {
    float4 selbox[SELCAP];        // 3.2 KB
    float selA[SELCAP];           // 0.8 KB
    uint64_t selkey[SELCAP];      // 1.6 KB
    uint64_t keys[KPAD];          // 70.1 KB
    uint64_t smask[2][64];        // 1 KB: suppressor-major intra-batch masks
    unsigned long long extC[2];   // single-word ext ballots per parity
    int hist[NBIN];               // 8 KB
    int binstart[NBIN];           // 8 KB
    int wavetot[NW];
    int Mshare, MtrShare, nselshare, prevNshare, doneflag;
};  // ~93 KB

__device__ __forceinline__ int iou_sup(float4 a, float aA, float4 b, float bA) {
    float x1 = fmaxf(a.x, b.x), y1 = fmaxf(a.y, b.y);
    float x2 = fminf(a.z, b.z), y2 = fminf(a.w, b.w);
    float iw = fmaxf(__fsub_rn(x2, x1), 0.0f);
    float ih = fmaxf(__fsub_rn(y2, y1), 0.0f);
    float inter = __fmul_rn(iw, ih);
    float uni = __fsub_rn(__fadd_rn(aA, bA), inter);
    return (double)inter > MIDD * (double)uni;
}

__device__ __forceinline__ float4 load_box(const float* __restrict__ img,
                                           int boxoff, uint64_t key) {
    if ((key >> 32) == 0) return make_float4(0.f, 0.f, 0.f, 0.f);
    uint32_t i = 0xFFFFFFFFu - (uint32_t)key;
    const float* bp = img + (size_t)i * LASTD + boxoff;
    return make_float4(bp[0], bp[1], bp[2], bp[3]);
}

__device__ __forceinline__ float box_area(float4 b) {
    return __fmul_rn(__fsub_rn(b.z, b.x), __fsub_rn(b.w, b.y));
}

__device__ __forceinline__ float4 shfl_box(float4 b, int c) {
    float4 r;
    r.x = __shfl(b.x, c); r.y = __shfl(b.y, c);
    r.z = __shfl(b.z, c); r.w = __shfl(b.w, c);
    return r;
}

__device__ __forceinline__ uint64_t shfl_xor_u64(uint64_t v, int m) {
    return (uint64_t)__shfl_xor((unsigned long long)v, m, 64);
}

// LDS-tiled layout pass: each block loads a 64-row x 102-col tile of one
// image COALESCED (float4), keeps the 21 needed columns in a padded LDS tile,
// then writes 64-element column segments COALESCED to confT/extraT. Replaces
// the r15 scatter version whose 4B writes touched ~64 lines per instruction.
__global__ __launch_bounds__(256) void transpose_conf(const float* __restrict__ yp,
                                                      float* __restrict__ confT,
                                                      float* __restrict__ extraT) {
    __shared__ float tile[TSLOT * TPITCH];
    const int blk = blockIdx.x;
    const int b = blk / NTILE;
    const int t0 = blk - b * NTILE;
    const int r0 = t0 * TROWS;
    const int nrow = (NBOX - r0) < TROWS ? (NBOX - r0) : TROWS;
    const int nflat4 = nrow * LASTD / 4;          // 102*nrow always /4
    const float4* src = (const float4*)(yp + ((size_t)b * NBOX + r0) * LASTD);

    for (int i4 = threadIdx.x; i4 < nflat4; i4 += 256) {
        float4 v = src[i4];
        int base = i4 * 4;
        #pragma unroll
        for (int k = 0; k < 4; ++k) {
            int f = base + k;
            int row = f / LASTD;
            int col = f - row * LASTD;
            float val = (k == 0) ? v.x : (k == 1) ? v.y : (k == 2) ? v.z : v.w;
            int slot = -1;
            if ((unsigned)(col - 1) < (unsigned)NCM1) slot = col - 1;
            else if (col == LASTD - 1) slot = NCM1;
            if (slot >= 0) tile[slot * TPITCH + row] = val;
        }
    }
    __syncthreads();

    for (int w = threadIdx.x; w < TSLOT * TROWS; w += 256) {
        int slot = w >> 6, ro = w & 63;
        int row = r0 + ro;
        if (ro < nrow) {
            float v = tile[slot * TPITCH + ro];
            if (slot < NCM1)
                confT[((size_t)b * NCM1 + slot) * CPAD + row] = v;
            else
                extraT[(size_t)b * CPAD + row] = v;
        }
    }
}

// 2048-bin counting sort of conf>0.5 candidates into (score desc, idx asc)
// order. TRM=true: only the top-NTR tranche (exact prefix of the full order).
template <bool TRM>
__device__ void build_keys_impl(const float* __restrict__ confsrc, int cstride,
                                SM& sm, int tid, int lane, int wav,
                                int& M, int& Mtr) {
    constexpr int PADT = TRM ? KPAD_TR : KPAD;
    float confs[NIT];
    #pragma unroll
    for (int it = 0; it < NIT; ++it) {
        int idx = it * THREADS + tid;
        confs[it] = (idx < NBOX) ? confsrc[(size_t)idx * cstride] : 0.0f;
    }
    sm.hist[tid] = 0; sm.hist[tid + THREADS] = 0;
    if (tid == 0) sm.MtrShare = 0;
    __syncthreads();

    #pragma unroll
    for (int it = 0; it < NIT; ++it) {
        int idx = it * THREADS + tid;
        if (idx < NBOX && confs[it] > CONF_TH) {
            int bin = (int)((__float_as_uint(confs[it]) - 0x3F000000u) >> 12);
            atomicAdd(&sm.hist[bin], 1);
        }
    }
    __syncthreads();

    int h0 = sm.hist[2 * tid], h1 = sm.hist[2 * tid + 1];
    int x = h0 + h1;
    int s = x;
    #pragma unroll
    for (int d = 1; d <= 32; d <<= 1) {
        int y = __shfl_down(s, d);
        if (lane + d < 64) s += y;
    }
    if (lane == 0) sm.wavetot[wav] = s;
    __syncthreads();
    int cross = 0;
    #pragma unroll
    for (int w = 0; w < NW; ++w)
        if (w > wav) cross += sm.wavetot[w];
    int Safter = cross + s - x;               // keys in bins strictly above
    sm.binstart[2 * tid + 1] = Safter;        // higher bin (higher score) first
    sm.binstart[2 * tid] = Safter + h1;
    if (tid == 0) sm.Mshare = cross + s;
    if (TRM) {
        int cand = 0;
        if (Safter < NTR && h1 > 0) cand = Safter + h1;
        int bs0 = Safter + h1;
        if (bs0 < NTR && h0 > 0) { int c2 = bs0 + h0; cand = cand > c2 ? cand : c2; }
        if (cand > 0) atomicMax(&sm.MtrShare, cand);
    }
    sm.hist[2 * tid] = 0; sm.hist[2 * tid + 1] = 0;  // reuse as scatter ctr
    __syncthreads();
    M = sm.Mshare;
    Mtr = TRM ? sm.MtrShare : M;

    #pragma unroll
    for (int it = 0; it < NIT; ++it) {
        int idx = it * THREADS + tid;
        if (idx < NBOX && confs[it] > CONF_TH) {
            uint32_t bits = __float_as_uint(confs[it]);
            int bin = (int)((bits - 0x3F000000u) >> 12);
            if (!TRM || sm.binstart[bin] < NTR) {
                int slot = sm.binstart[bin] + atomicAdd(&sm.hist[bin], 1);
                if (!TRM || slot < PADT)
                    sm.keys[slot] = ((uint64_t)bits << 32) |
                                    (uint32_t)(0xFFFFFFFFu - (uint32_t)idx);
            }
        }
    }
    __syncthreads();
    int Mp = Mtr < PADT ? Mtr : PADT;
    for (int m = Mp + tid; m < PADT; m += THREADS) sm.keys[m] = 0;
    for (int f = tid; f < NBIN; f += THREADS) {
        int s0 = sm.binstart[f], h = sm.hist[f];
        if (TRM && (s0 >= NTR || s0 + h > PADT)) continue;
        for (int i2 = 1; i2 < h; ++i2) {
            uint64_t key = sm.keys[s0 + i2];
            int j = i2 - 1;
            while (j >= 0 && sm.keys[s0 + j] < key) {
                sm.keys[s0 + j + 1] = sm.keys[s0 + j];
                --j;
            }
            sm.keys[s0 + j + 1] = key;
        }
    }
    __syncthreads();
}

// Two-barrier pipelined greedy scan (r12 structure + r17 extC): chunk-major
// full-check, ext-gated suppressor masks. Exactly replicates the reference's
// argmax+suppress loop over keys[0..KPADT).
template <int KPADT, int NBATCHT>
__device__ int greedy_scan(const float* __restrict__ img, int boxoff, SM& sm,
                           int tid, int lane, int wav) {
    uint64_t keyC = sm.keys[lane];
    uint64_t keyN = sm.keys[64 + lane];
    float4 boxC = load_box(img, boxoff, keyC);
    float4 boxN = load_box(img, boxoff, keyN);
    float aC = box_area(boxC), aN = box_area(boxN);
    #pragma unroll
    for (int tt = 0; tt < 4; ++tt) {
        int c = wav + tt * NW;
        float4 cb = shfl_box(boxC, c);
        float ca = __shfl(aC, c);
        uint64_t row = 0;
        if (ca > 0.0f)   // wave-uniform
            row = __ballot(lane < c && iou_sup(cb, ca, boxC, aC));
        if (lane == 0) sm.smask[0][c] = row;
    }
    if (tid == 0) { sm.extC[0] = 0ull; sm.extC[1] = 0ull; }
    __syncthreads();

    int nsel = 0, prevN = 0;
    bool done = false;
    for (int i = 0; i < NBATCHT && !done; ++i) {
        const int p = i & 1;
        const bool vC = (keyC >> 32) != 0;
        // delta-check cur vs accepts [prevN, nsel)
        {
            int sup = 0;
            for (int j = prevN + wav; j < nsel; j += NW)
                sup |= iou_sup(boxC, aC, sm.selbox[j], sm.selA[j]);
            unsigned long long bal = __ballot(vC && sup);
            if (lane == 0 && bal) atomicOr(&sm.extC[p], bal);
        }
        int f0 = (i + 2) * 64;
        uint64_t key2 = (f0 < KPADT) ? sm.keys[f0 + lane] : 0;
        float4 box2 = load_box(img, boxoff, key2);
        float a2 = box_area(box2);
        __syncthreads();  // [1] extC[p] complete; snapshot nsel
        const int nselPre = nsel;
        if (wav == 0) {
            unsigned long long V = __ballot(vC);
            unsigned long long E = sm.extC[p];
            if (lane == 0) sm.extC[p] = 0ull;
            uint64_t smc = sm.smask[p][lane];
            uint64_t alive = ~(E | ~V);
            uint64_t accm = 0;
            int cnt = nsel;
            while (alive && cnt < SELCAP) {
                int t = __ffsll((unsigned long long)alive) - 1;
                uint64_t bit = 1ull << t;
                accm |= bit;
                cnt++;
                unsigned long long kill = __ballot((smc >> t) & 1ull);
                alive &= ~(kill | bit);
            }
            if ((accm >> lane) & 1ull) {
                int pos = nsel + __popcll(accm & ((1ull << lane) - 1ull));
                sm.selbox[pos] = boxC;
                sm.selA[pos] = aC;
                sm.selkey[pos] = keyC;
            }
            if (lane == 0) {
                sm.nselshare = cnt;
                sm.prevNshare = nsel;
                sm.doneflag = (cnt >= SELCAP) || (V != ~0ull);
            }
        } else {
            // chunk-major full-check of batch i+1 vs [0..nselPre)
            float4 cb[5];
            float ca[5];
            unsigned amask = 0;
            #pragma unroll
            for (int k = 0; k < 5; ++k) {
                int c = (wav - 1) + k * (NW - 1);
                float4 t4 = make_float4(0.f, 0.f, 0.f, 0.f);
                float tA = 0.0f;
                if (c < 64) {
                    t4 = shfl_box(boxN, c);
                    tA = __shfl(aN, c);
                }
                cb[k] = t4; ca[k] = tA;
                if (c < 64 && tA > 0.0f) amask |= 1u << k;
            }
            unsigned long long sb = 0;
            for (int j0 = 0; j0 < nselPre && amask; j0 += 64) {
                int j = j0 + lane;
                bool jv = j < nselPre;
                float4 sbx = sm.selbox[jv ? j : 0];
                float sA = sm.selA[jv ? j : 0];
                #pragma unroll
                for (int k = 0; k < 5; ++k) {
                    if (!((amask >> k) & 1u)) continue;   // wave-uniform
                    int hit = jv && iou_sup(cb[k], ca[k], sbx, sA);
                    if (__ballot(hit)) {
                        amask &= ~(1u << k);
                        sb |= 1ull << ((wav - 1) + k * (NW - 1));
                    }
                }
            }
            #pragma unroll
            for (int k = 0; k < 5; ++k) {
                if (!((amask >> k) & 1u)) continue;
                int c = (wav - 1) + k * (NW - 1);
                uint64_t row = __ballot(lane < c && iou_sup(cb[k], ca[k], boxN, aN));
                if (lane == 0) sm.smask[p ^ 1][c] = row;
            }
            if (lane == 0 && sb) atomicOr(&sm.extC[p ^ 1], sb);
        }
        __syncthreads();  // [2] accepts, counters, smask, extC published
        nsel = sm.nselshare;
        prevN = sm.prevNshare;
        done = sm.doneflag != 0;
        keyC = keyN; boxC = boxN; aC = aN;
        keyN = key2; boxN = box2; aN = a2;
    }
    return nsel;
}

// Emit ranks [0,EMITN); zeros past nsel.
__device__ void emit_rows(const float* __restrict__ extrasrc, int estride,
                          int cm1, SM& sm, int nsel, float* __restrict__ rows,
                          int task, int tid) {
    float* out0 = rows + (size_t)task * MAXOUT * 7;
    for (int r = tid; r < EMITN; r += THREADS) {
        float* o = out0 + (size_t)r * 7;
        if (r < nsel) {
            uint64_t key = sm.selkey[r];
            uint32_t i = 0xFFFFFFFFu - (uint32_t)key;
            float4 bx = sm.selbox[r];
            o[0] = (float)(cm1 + 1);
            o[1] = __uint_as_float((uint32_t)(key >> 32));
            o[2] = bx.x;
            o[3] = bx.y;
            o[4] = bx.z;
            o[5] = bx.w;
            o[6] = extrasrc[(size_t)i * estride];
        } else {
            #pragma unroll
            for (int q = 0; q < 7; ++q) o[q] = 0.0f;
        }
    }
}

// Main NMS kernel: tranche-sorted fast path with exact full fallback.
__global__ __launch_bounds__(THREADS) void nms_fast(const float* __restrict__ yp,
                                                    const float* __restrict__ confT,
                                                    const float* __restrict__ extraT,
                                                    float* __restrict__ rows) {
    __shared__ SM sm;
    const int task = blockIdx.x;
    const int b = task / NCM1;
    const int cm1 = task % NCM1;
    const int tid = threadIdx.x;
    const int lane = tid & 63;
    const int wav = tid >> 6;
    const float* img = yp + (size_t)b * NBOX * LASTD;
    const float* conf = confT + (size_t)task * CPAD;
    const int boxoff = NCL + 4 * cm1;

    int M, Mtr;
    build_keys_impl<true>(conf, 1, sm, tid, lane, wav, M, Mtr);
    int nsel = -1;
    if (Mtr <= KPAD_TR) {          // no bin overflow (block-uniform)
        nsel = greedy_scan<KPAD_TR, NBATCH_TR>(img, boxoff, sm, tid, lane, wav);
        if (nsel < SELCAP && Mtr < M) nsel = -1;  // tranche exhausted
    }
    if (nsel < 0) {                // exact full path (P ~ 0)
        build_keys_impl<false>(conf, 1, sm, tid, lane, wav, M, Mtr);
        nsel = greedy_scan<KPAD, NBATCH>(img, boxoff, sm, tid, lane, wav);
    }
    emit_rows(extraT + (size_t)b * CPAD, 1, cm1, sm, nsel, rows, task, tid);
}

// Fallback monolith (direct strided gathers, full sort) if ws too small.
__global__ __launch_bounds__(THREADS) void nms_mono(const float* __restrict__ yp,
                                                    float* __restrict__ rows) {
    __shared__ SM sm;
    const int task = blockIdx.x;
    const int b = task / NCM1;
    const int cm1 = task % NCM1;
    const int tid = threadIdx.x;
    const float* img = yp + (size_t)b * NBOX * LASTD;
    int M, Mtr;
    build_keys_impl<false>(img + 1 + cm1, LASTD, sm, tid, tid & 63, tid >> 6,
                           M, Mtr);
    int nsel = greedy_scan<KPAD, NBATCH>(img, NCL + 4 * cm1, sm, tid,
                                         tid & 63, tid >> 6);
    emit_rows(img + (LASTD - 1), LASTD, cm1, sm, nsel, rows, task, tid);
}

// One block per image: top-200 by (conf desc, flat idx asc). Per-class lists
// are score-desc; top-200 never needs within-class rank >= 256: 32 lists x
// 256 keys, 5 rounds of bitonic top-256 merges; j<=32 merge stages fused in
// registers via shfl_xor (lane = elem&63; (t&j)==0 takes max — identical to
// the LDS compare-swap), 9 barrier passes/round -> 4.
__global__ __launch_bounds__(THREADS) void topk_per_image(const float* __restrict__ rows,
                                                          float* __restrict__ out) {
    __shared__ uint64_t K[8192];
    const int b = blockIdx.x;
    const int tid = threadIdx.x;
    const float* rb = rows + (size_t)b * (NCM1 * MAXOUT) * 7;

    for (int xx = tid; xx < 8192; xx += THREADS) {
        int list = xx >> 8, r = xx & 255;
        uint64_t k = 0;
        if (list < NCM1) {
            int flat = list * MAXOUT + r;
            float conf = rb[(size_t)flat * 7 + 1];
            k = ((uint64_t)__float_as_uint(conf) << 32) |
                (uint32_t)(0xFFFFFFFFu - (uint32_t)flat);
        }
        K[xx] = k;
    }
    __syncthreads();

    for (int round = 0; round < 5; ++round) {
        int npairs = 16 >> round;
        int sep = 256 << round;
        for (int w = tid; w < npairs * 256; w += THREADS) {
            int p = w >> 8, t = w & 255;
            int A = p * 2 * sep;
            uint64_t a = K[A + t];
            uint64_t c = K[A + sep + 255 - t];
            K[A + t] = a > c ? a : c;
        }
        __syncthreads();
        for (int j = 128; j >= 64; j >>= 1) {
            for (int w = tid; w < npairs * 128; w += THREADS) {
                int p = w >> 7, q = w & 127;
                int t = ((q & ~(j - 1)) << 1) | (q & (j - 1));
                int A = p * 2 * sep;
                uint64_t x0 = K[A + t];
                uint64_t x1 = K[A + t + j];
                if (x0 < x1) { K[A + t] = x1; K[A + t + j] = x0; }
            }
            __syncthreads();
        }
        for (int w = tid; w < npairs * 256; w += THREADS) {
            int p = w >> 8, t = w & 255;
            int xI = p * 2 * sep + t;
            uint64_t v = K[xI];
            #pragma unroll
            for (int j = 32; j >= 1; j >>= 1) {
                uint64_t pr = shfl_xor_u64(v, j);
                uint64_t mx = v > pr ? v : pr;
                uint64_t mn = v > pr ? pr : v;
                v = ((t & j) == 0) ? mx : mn;
            }
            K[xI] = v;
        }
        __syncthreads();
    }

    if (tid < TOPK) {
        uint64_t key = K[tid];
        uint32_t flat = 0xFFFFFFFFu - (uint32_t)key;
        const float* src = rb + (size_t)flat * 7;
        float* o = out + ((size_t)b * TOPK + tid) * 7;
        #pragma unroll
        for (int q = 0; q < 7; ++q) o[q] = src[q];
    }
}

extern "C" void kernel_launch(void* const* d_in, const int* in_sizes, int n_in,
                              void* d_out, int out_size, void* d_ws, size_t ws_size,
                              hipStream_t stream) {
    const float* yp = (const float*)d_in[0];
    float* rows = (float*)d_ws;
    const size_t rowsB = (size_t)NTASK * MAXOUT * 7 * sizeof(float);   // 1.792 MB
    float* confT = (float*)((char*)d_ws + rowsB);
    const size_t confB = (size_t)NTASK * CPAD * sizeof(float);         // 5.59 MB
    float* extraT = (float*)((char*)confT + confB);
    const size_t extraB = (size_t)NB * CPAD * sizeof(float);           // 0.28 MB
    const size_t need = rowsB + confB + extraB;                        // ~7.7 MB
    float* out = (float*)d_out;

    if (ws_size >= need) {
        hipLaunchKernelGGL(transpose_conf, dim3(NB * NTILE), dim3(256), 0,
                           stream, yp, confT, extraT);
        hipLaunchKernelGGL(nms_fast, dim3(NTASK), dim3(THREADS), 0, stream,
                           yp, confT, extraT, rows);
    } else {
        hipLaunchKernelGGL(nms_mono, dim3(NTASK), dim3(THREADS), 0, stream,
                           yp, rows);
    }
    hipLaunchKernelGGL(topk_per_image, dim3(NB), dim3(THREADS), 0, stream,
                       rows, out);
}